// Round 7
// baseline (292.259 us; speedup 1.0000x reference)
//
#include <hip/hip_runtime.h>
#include <math.h>
#include <stdint.h>

#define H_DIM 1024
#define NH 16
#define HD 64
#define B_DIM 2
#define L_DIM 2048
#define M_TOT (B_DIM * L_DIM)   // 4096

typedef __bf16 bf16_t;
typedef __bf16 bf16x8 __attribute__((ext_vector_type(8)));
typedef __bf16 bf16x4 __attribute__((ext_vector_type(4)));
typedef float  f32x4  __attribute__((ext_vector_type(4)));

#define AS1 const __attribute__((address_space(1))) void*
#define AS3 __attribute__((address_space(3))) void*

// ---------------------------------------------------------------------------
// Kernel 0: cast x (4M fp32) and Wq|Wk|Wv (3x1M fp32) to one bf16 buffer.
// Block 0 additionally zeroes the 512 combine flags for this iteration
// (kernel-boundary ordering makes them visible to attn_mfma).
// ---------------------------------------------------------------------------
__global__ __launch_bounds__(256)
void cast_all(const float* __restrict__ x,
              const float* __restrict__ Wq, const float* __restrict__ Wk,
              const float* __restrict__ Wv, bf16_t* __restrict__ dst,
              int* __restrict__ flags)
{
    if (blockIdx.x == 0 && threadIdx.x < 128) {
        int4 z; z.x = 0; z.y = 0; z.z = 0; z.w = 0;
        *(int4*)(flags + threadIdx.x * 4) = z;
    }
    const size_t idx = ((size_t)blockIdx.x * 256 + threadIdx.x) * 4;
    const float* src;
    size_t off;
    if (idx < (size_t)M_TOT * H_DIM) { src = x; off = idx; }
    else {
        size_t j = idx - (size_t)M_TOT * H_DIM;
        int z = (int)(j >> 20);
        off = j & ((1u << 20) - 1);
        src = (z == 0) ? Wq : (z == 1) ? Wk : Wv;
    }
    const float4 v = *(const float4*)(src + off);
    bf16x4 o;
    o[0] = (bf16_t)v.x; o[1] = (bf16_t)v.y;
    o[2] = (bf16_t)v.z; o[3] = (bf16_t)v.w;
    *(bf16x4*)(dst + idx) = o;
}

// ---------------------------------------------------------------------------
// Kernel 1: QKV GEMM v2 — measured-best version (UNCHANGED).
// One block = one (bm,bn) x ALL THREE weights; triple-buffered LDS + 2-deep
// DMA prefetch + vmcnt(8) own-slice wait THEN barrier.
// z=0 -> Q [bh][l][d], z=1 -> K [bh][l][d], z=2 -> V^T [bh][d][l].
// ---------------------------------------------------------------------------
__global__ __launch_bounds__(256, 1)
void qkv_mfma(const bf16_t* __restrict__ xb, const bf16_t* __restrict__ wb,
              const float* __restrict__ bq, const float* __restrict__ bk,
              const float* __restrict__ bv,
              bf16_t* __restrict__ qb, bf16_t* __restrict__ kb,
              bf16_t* __restrict__ vt)
{
    __shared__ bf16_t As0[128 * 32];
    __shared__ bf16_t As1[128 * 32];
    __shared__ bf16_t As2[128 * 32];
    __shared__ bf16_t Bs0[3][128 * 32];
    __shared__ bf16_t Bs1[3][128 * 32];
    __shared__ bf16_t Bs2[3][128 * 32];

    const int tid = threadIdx.x;
    const int n   = blockIdx.x;          // 0..255
    const int bn  = (n & 7) * 128;       // XCD-local W slice (round-robin)
    const int bm  = (n >> 3) * 128;

    const int wave = tid >> 6;
    const int lane = tid & 63;
    const int lc   = lane & 15;
    const int quad = lane >> 4;
    const int wm   = wave >> 1;
    const int wn   = wave & 1;

    f32x4 acc[3][4][4];
    #pragma unroll
    for (int z = 0; z < 3; ++z)
        #pragma unroll
        for (int i = 0; i < 4; ++i)
            #pragma unroll
            for (int j = 0; j < 4; ++j)
                acc[z][i][j] = (f32x4){0.f, 0.f, 0.f, 0.f};

    const int srow = tid >> 2;
    const int sseg = tid & 3;
    const bf16_t* gA = xb + (size_t)(bm + srow) * H_DIM + (sseg ^ (srow & 3)) * 8;
    const bf16_t* gB = wb + (size_t)(bn + srow) * H_DIM + (sseg ^ (srow & 3)) * 8;
    const int woff = wave * 1024;   // bytes per wave slice of a 4 KB half-tile

    auto stage = [&](int k0, bf16_t* A_, bf16_t (*B_)[128 * 32]) {
        __builtin_amdgcn_global_load_lds((AS1)(gA + k0),
            (AS3)((char*)A_ + woff), 16, 0, 0);
        __builtin_amdgcn_global_load_lds((AS1)(gA + k0 + (size_t)64 * H_DIM),
            (AS3)((char*)A_ + woff + 4096), 16, 0, 0);
        #pragma unroll
        for (int z = 0; z < 3; ++z) {
            const bf16_t* g = gB + (size_t)z * H_DIM * H_DIM + k0;
            __builtin_amdgcn_global_load_lds((AS1)(g),
                (AS3)((char*)B_[z] + woff), 16, 0, 0);
            __builtin_amdgcn_global_load_lds((AS1)(g + (size_t)64 * H_DIM),
                (AS3)((char*)B_[z] + woff + 4096), 16, 0, 0);
        }
    };

    const int slot = (quad ^ (lc & 3)) * 8;
    auto compute = [&](const bf16_t* A_, const bf16_t (*B_)[128 * 32]) {
        bf16x8 a[4];
        #pragma unroll
        for (int mi = 0; mi < 4; ++mi)
            a[mi] = *(const bf16x8*)(A_ + (wm * 64 + mi * 16 + lc) * 32 + slot);
        #pragma unroll
        for (int z = 0; z < 3; ++z) {
            bf16x8 b[4];
            #pragma unroll
            for (int ni = 0; ni < 4; ++ni)
                b[ni] = *(const bf16x8*)(B_[z] + (wn * 64 + ni * 16 + lc) * 32 + slot);
            #pragma unroll
            for (int mi = 0; mi < 4; ++mi)
                #pragma unroll
                for (int ni = 0; ni < 4; ++ni)
                    acc[z][mi][ni] = __builtin_amdgcn_mfma_f32_16x16x32_bf16(
                        a[mi], b[ni], acc[z][mi][ni], 0, 0, 0);
        }
    };

    auto step = [&](int kk, bf16_t* cA, bf16_t (*cB)[128 * 32],
                    bf16_t* nA, bf16_t (*nB)[128 * 32], bool doStage) {
        __builtin_amdgcn_s_waitcnt(0x0F78);   // vmcnt(8): 8 newest may remain
        __builtin_amdgcn_s_barrier();
        if (doStage) stage((kk + 2) * 32, nA, nB);
        compute(cA, cB);
    };

    stage(0,  As0, Bs0);
    stage(32, As1, Bs1);
    #pragma unroll 1
    for (int t = 0; t < 10; ++t) {
        const int kk = t * 3;
        step(kk,     As0, Bs0, As2, Bs2, true);
        step(kk + 1, As1, Bs1, As0, Bs0, true);
        step(kk + 2, As2, Bs2, As1, Bs1, true);
    }
    step(30, As0, Bs0, As2, Bs2, false);      // set 32 does not exist
    __builtin_amdgcn_s_waitcnt(0x0F70);       // vmcnt(0): set 31 landed
    __builtin_amdgcn_s_barrier();
    compute(As1, Bs1);                        // set 31

    // --- epilogue: bias + scatter per z ---
    const int nb = bn + wn * 64;
    #pragma unroll
    for (int z = 0; z < 3; ++z) {
        const float* bias = (z == 0) ? bq : (z == 1) ? bk : bv;
        float biasv[4];
        #pragma unroll
        for (int ni = 0; ni < 4; ++ni) biasv[ni] = bias[nb + ni * 16 + lc];

        #pragma unroll
        for (int mi = 0; mi < 4; ++mi) {
            const int m0 = bm + wm * 64 + mi * 16 + quad * 4;
            if (z == 2) {
                const int b_ = m0 >> 11;
                const int l0 = m0 & 2047;
                #pragma unroll
                for (int ni = 0; ni < 4; ++ni) {
                    const int nn = nb + ni * 16 + lc;
                    const int h = nn >> 6, d = nn & 63;
                    bf16x4 pk;
                    #pragma unroll
                    for (int r = 0; r < 4; ++r)
                        pk[r] = (bf16_t)(acc[z][mi][ni][r] + biasv[ni]);
                    *(bf16x4*)(vt + (((size_t)(b_ * NH + h)) * HD + d) * L_DIM + l0) = pk;
                }
            } else {
                bf16_t* dst = (z == 0) ? qb : kb;
                #pragma unroll
                for (int r = 0; r < 4; ++r) {
                    const int m  = m0 + r;
                    const int b_ = m >> 11;
                    const int l  = m & 2047;
                    #pragma unroll
                    for (int ni = 0; ni < 4; ++ni) {
                        const int nn = nb + ni * 16 + lc;
                        const int h = nn >> 6, d = nn & 63;
                        dst[(((size_t)(b_ * NH + h)) * L_DIM + l) * HD + d] =
                            (bf16_t)(acc[z][mi][ni][r] + biasv[ni]);
                    }
                }
            }
        }
    }
}

// ---------------------------------------------------------------------------
// Kernel 2: MFMA flash attention — ROUND-15: r14 inner loop UNCHANGED
// (mask-LDS + setprio verified: 58.4 -> 51.4us).  NEW: the combine kernel
// is fused in as a last-finisher epilogue — partner key-half blocks (n,
// n+512, same XCD by swizzle) sync via device atomics; the second one
// normalizes out = (O0+O1)/(l0+l1) from L2-hot partials, removing the
// 4th dispatch and its ~48MB round trip.
// ---------------------------------------------------------------------------
#define EXP_C   0.180336879f   /* 0.125 * log2(e) */
#define LOG2E   1.442695041f
#define EXP_SH  11.541560327f  /* 8 * log2(e) */

__device__ __forceinline__ void attn_tile32(
    int kbase, bool pre,
    const bf16_t* curK, const bf16_t* curV,
    bf16_t* nxtK, bf16_t* nxtV,
    const bf16_t* gKw, const bf16_t* gVw, int wo,
    bf16_t* Ps, const float* mvsL, int lc, int quad,
    const bf16x8 (&bQ)[2][2], f32x4 (&o)[2][4], float (&rs)[2])
{
    // Own DMA slice of THIS tile (issued one tile ago) landed, then barrier:
    // all waves' slices landed AND all waves finished reading the buffer the
    // upcoming prefetch will overwrite.
    __builtin_amdgcn_s_waitcnt(0x0F70);   // vmcnt(0)
    __builtin_amdgcn_s_barrier();

    const int e = lc & 7;

    // --- K fragment reads (swizzled) ---
    bf16x8 kf[2][2];
    #pragma unroll
    for (int ni = 0; ni < 2; ++ni) {
        const bf16_t* p = curK + (ni * 16 + lc) * 64;
        kf[ni][0] = *(const bf16x8*)(p + ((quad ^ e) << 3));
        kf[ni][1] = *(const bf16x8*)(p + (((quad ^ e) ^ 4) << 3));
    }

    // --- fire-and-forget DMA of the next tile (this wave's 1+1 slices) ---
    if (pre) {
        const int nk = kbase + 32;
        __builtin_amdgcn_global_load_lds(
            (AS1)(gKw + (size_t)nk * 64),
            (AS3)(nxtK + wo), 16, 0, 0);
        __builtin_amdgcn_global_load_lds(
            (AS1)(gVw + nk),
            (AS3)(nxtV + wo), 16, 0, 0);
    }

    // --- mask bias: precomputed in LDS (broadcast reads, no VALU) ---
    f32x4 mvs[2];
    #pragma unroll
    for (int ni = 0; ni < 2; ++ni)
        mvs[ni] = *(const f32x4*)(mvsL + kbase + ni * 16 + quad * 4);

    // --- S^T = K Q^T, exp2, P write (128B-row combined layout) ---
    #pragma unroll
    for (int f = 0; f < 2; ++f) {
        f32x4 s[2];
        __builtin_amdgcn_s_setprio(1);
        #pragma unroll
        for (int ni = 0; ni < 2; ++ni) {
            f32x4 t = (f32x4){0.f, 0.f, 0.f, 0.f};
            t = __builtin_amdgcn_mfma_f32_16x16x32_bf16(kf[ni][0], bQ[f][0], t, 0, 0, 0);
            t = __builtin_amdgcn_mfma_f32_16x16x32_bf16(kf[ni][1], bQ[f][1], t, 0, 0, 0);
            s[ni] = t;
        }
        __builtin_amdgcn_s_setprio(0);
        float acc = 0.f;
        #pragma unroll
        for (int ni = 0; ni < 2; ++ni) {
            bf16x4 pk;
            #pragma unroll
            for (int r = 0; r < 4; ++r) {
                const float p = __builtin_amdgcn_exp2f(s[ni][r] * EXP_C + mvs[ni][r]);
                acc += p;
                pk[r] = (bf16_t)p;
            }
            const int c = f * 4 + ni * 2 + (quad >> 1);     // logical chunk
            *(bf16x4*)(Ps + lc * 64 + ((c ^ e) << 3) + ((quad & 1) << 2)) = pk;
        }
        rs[f] += acc;
    }

    // --- V fragment reads (pair-interleaved swizzle) ---
    bf16x8 vf[4];
    const int e2 = lc >> 1;
    #pragma unroll
    for (int dg = 0; dg < 4; ++dg) {
        const int p  = dg * 8 + (lc >> 1);
        const int ch = (((lc & 1) << 2) + quad) ^ e2;
        vf[dg] = *(const bf16x8*)(curV + p * 64 + (ch << 3));
    }

    // --- O^T += V^T P^T ---
    #pragma unroll
    for (int f = 0; f < 2; ++f) {
        const int c = f * 4 + quad;
        const bf16x8 bP = *(const bf16x8*)(Ps + lc * 64 + ((c ^ e) << 3));
        __builtin_amdgcn_s_setprio(1);
        #pragma unroll
        for (int dg = 0; dg < 4; ++dg)
            o[f][dg] = __builtin_amdgcn_mfma_f32_16x16x32_bf16(vf[dg], bP, o[f][dg], 0, 0, 0);
        __builtin_amdgcn_s_setprio(0);
    }
}

__global__ __launch_bounds__(256, 4)
void attn_mfma(const bf16_t* __restrict__ qb, const bf16_t* __restrict__ kb,
               const bf16_t* __restrict__ vt, const float* __restrict__ mask,
               float* __restrict__ out, float* __restrict__ o1,
               float* __restrict__ l0, float* __restrict__ l1,
               int* __restrict__ flags)
{
    __shared__ bf16_t Ks0[32 * 64];
    __shared__ bf16_t Ks1[32 * 64];
    __shared__ bf16_t Vs0[32 * 64];
    __shared__ bf16_t Vs1[32 * 64];
    __shared__ bf16_t Ps[4][16 * 64];   // per-wave P scratch
    __shared__ float  Ms[1024];         // precomputed mask*LOG2E - EXP_SH
    __shared__ int    sOld;

    const int tid  = threadIdx.x;
    const int wave = tid >> 6;         // 0..3
    const int lane = tid & 63;
    const int lc   = lane & 15;
    const int quad = lane >> 4;
    const int rl   = lane >> 3;        // DMA row-in-group
    const int sg   = lane & 7;         // DMA 16B-seg (pre-swizzle)

    // XCD-locality decode: all blocks of a head on one XCD; partner
    // key-half blocks n and n+512 share the XCD (512 % 8 == 0).
    const int n    = blockIdx.x;       // 0..1023
    const int bh   = (n & 7) * 4 + ((n >> 3) & 3);
    const int q0   = ((n >> 5) & 15) * 128 + wave * 32;
    const int ks   = (n >> 9) & 1;     // key half
    const int k0   = ks << 10;         // 0 or 1024
    const int b_   = bh >> 4;
    const int h    = bh & 15;

    bf16_t* Psw = Ps[wave];

    // Q fragments (B-operand of S^T): frag f holds q = q0 + f*16 + lc
    bf16x8 bQ[2][2];
    #pragma unroll
    for (int f = 0; f < 2; ++f) {
        const bf16_t* Qp = qb + ((size_t)bh * L_DIM + q0 + f * 16 + lc) * HD + quad * 8;
        bQ[f][0] = *(const bf16x8*)(Qp);
        bQ[f][1] = *(const bf16x8*)(Qp + 32);
    }

    const bf16_t* Kbase = kb + (size_t)bh * L_DIM * HD;   // [key][d]
    const bf16_t* Vbase = vt + (size_t)bh * HD * L_DIM;   // [d][key]
    const float*  mrow  = mask + (size_t)b_ * L_DIM + k0;

    // Precompute mask bias for this block's 1024 keys (shared by all waves).
    {
        const float4 m4 = *(const float4*)(mrow + tid * 4);
        f32x4 w;
        w[0] = m4.x * LOG2E - EXP_SH;
        w[1] = m4.y * LOG2E - EXP_SH;
        w[2] = m4.z * LOG2E - EXP_SH;
        w[3] = m4.w * LOG2E - EXP_SH;
        *(f32x4*)(Ms + tid * 4) = w;
    }

    // Per-lane DMA source bases; each wave owns 1 of the 4 K slices
    // (8 keys) and 1 of the 4 V slices (16 d-rows).
    const int cV = sg ^ rl;
    const bf16_t* gKw = Kbase + (size_t)(k0 + wave * 8 + rl) * 64 + (sg ^ rl) * 8;
    const bf16_t* gVw = Vbase + k0
                      + (size_t)(wave * 16 + rl * 2 + (cV >> 2)) * L_DIM
                      + (cV & 3) * 8;
    const int wo = wave * 512;         // element offset of this wave's slice

    f32x4 o[2][4];
    #pragma unroll
    for (int f = 0; f < 2; ++f)
        #pragma unroll
        for (int dg = 0; dg < 4; ++dg) o[f][dg] = (f32x4){0.f, 0.f, 0.f, 0.f};
    float rs[2] = {0.f, 0.f};

    // Prologue: DMA tile 0 (this wave's slices) into buffer 0.
    __builtin_amdgcn_global_load_lds((AS1)(gKw), (AS3)(Ks0 + wo), 16, 0, 0);
    __builtin_amdgcn_global_load_lds((AS1)(gVw), (AS3)(Vs0 + wo), 16, 0, 0);

    __syncthreads();   // Ms visible to all waves (full lgkm drain + barrier)

    #pragma unroll 1
    for (int t2 = 0; t2 < 16; ++t2) {
        const int kb0 = t2 * 64;
        attn_tile32(kb0,      true,     Ks0, Vs0, Ks1, Vs1, gKw, gVw, wo, Psw,
                    Ms, lc, quad, bQ, o, rs);
        attn_tile32(kb0 + 32, t2 < 15,  Ks1, Vs1, Ks0, Vs0, gKw, gVw, wo, Psw,
                    Ms, lc, quad, bQ, o, rs);
    }

    // --- epilogue: reduce l across quads, write UNNORMALIZED partial ---
    float* obase = (ks == 0) ? out : o1;
    float* lbase = (ks == 0) ? l0  : l1;
    #pragma unroll
    for (int f = 0; f < 2; ++f) {
        float l = rs[f];
        l += __shfl_xor(l, 16);
        l += __shfl_xor(l, 32);
        if (quad == 0)
            lbase[(size_t)bh * L_DIM + q0 + f * 16 + lc] = l;
        float* orow = obase + ((size_t)(b_ * L_DIM + q0 + f * 16 + lc)) * H_DIM
                    + h * HD + quad * 4;
        #pragma unroll
        for (int dg = 0; dg < 4; ++dg)
            *(f32x4*)(orow + dg * 16) = o[f][dg];
    }

    // --- fused combine: last finisher of the (n, n+512) pair normalizes ---
    __threadfence();                     // own stores -> device coherence pt
    __syncthreads();                     // all threads' stores fenced
    if (tid == 0) sOld = atomicAdd(&flags[n & 511], 1);
    __syncthreads();
    if (sOld == 1) {
        // Partner's release (fence before its atomic) ordered its partials
        // before our acquire; partner addresses never read before -> no
        // stale L1/L2 lines.
        #pragma unroll
        for (int f = 0; f < 2; ++f) {
            const size_t ridx = (size_t)bh * L_DIM + q0 + f * 16 + lc;
            const float inv = 1.0f / (l0[ridx] + l1[ridx]);
            const size_t oidx = ((size_t)(b_ * L_DIM + q0 + f * 16 + lc)) * H_DIM
                              + h * HD + quad * 4;
            float* orow = out + oidx;
            const float* prow = o1 + oidx;
            #pragma unroll
            for (int dg = 0; dg < 4; ++dg) {
                f32x4 a = *(const f32x4*)(orow + dg * 16);
                const f32x4 b = *(const f32x4*)(prow + dg * 16);
                a = (a + b) * inv;
                *(f32x4*)(orow + dg * 16) = a;
            }
        }
    }
}

// ---------------------------------------------------------------------------
extern "C" void kernel_launch(void* const* d_in, const int* in_sizes, int n_in,
                              void* d_out, int out_size, void* d_ws, size_t ws_size,
                              hipStream_t stream) {
    const float* hidden = (const float*)d_in[0];
    const float* mask   = (const float*)d_in[1];
    const float* Wq     = (const float*)d_in[2];
    const float* bq     = (const float*)d_in[3];
    const float* Wk     = (const float*)d_in[4];
    const float* bk     = (const float*)d_in[5];
    const float* Wv     = (const float*)d_in[6];
    const float* bv     = (const float*)d_in[7];
    float* out = (float*)d_out;

    const size_t XN = (size_t)M_TOT * H_DIM;     // 4,194,304
    const size_t WN = (size_t)3 * H_DIM * H_DIM; // 3,145,728
    bf16_t* xwb = (bf16_t*)d_ws;
    bf16_t* qb  = xwb + XN + WN;
    bf16_t* kb  = qb + XN;
    bf16_t* vt  = kb + XN;
    float*  o1  = (float*)(vt + XN);             // key-half-1 partial O (fp32)
    float*  l0  = o1 + XN;                       // 65536 f32 each
    float*  l1  = l0 + (size_t)B_DIM * NH * L_DIM;
    int*    flags = (int*)(l1 + (size_t)B_DIM * NH * L_DIM);  // 512 ints

    cast_all<<<(int)((XN + WN) / 1024), 256, 0, stream>>>(hidden, Wq, Wk, Wv,
                                                          xwb, flags);

    qkv_mfma<<<256, 256, 0, stream>>>(xwb, xwb + XN, bq, bk, bv, qb, kb, vt);

    attn_mfma<<<1024, 256, 0, stream>>>(qb, kb, vt, mask, out, o1, l0, l1,
                                        flags);
}

// Round 8
// 171.360 us; speedup vs baseline: 1.7055x; 1.7055x over previous
//
#include <hip/hip_runtime.h>
#include <math.h>
#include <stdint.h>

#define H_DIM 1024
#define NH 16
#define HD 64
#define B_DIM 2
#define L_DIM 2048
#define M_TOT (B_DIM * L_DIM)   // 4096

typedef __bf16 bf16_t;
typedef __bf16 bf16x8 __attribute__((ext_vector_type(8)));
typedef __bf16 bf16x4 __attribute__((ext_vector_type(4)));
typedef float  f32x4  __attribute__((ext_vector_type(4)));

#define AS1 const __attribute__((address_space(1))) void*
#define AS3 __attribute__((address_space(3))) void*

// ---------------------------------------------------------------------------
// Kernel 0: cast x (4M fp32) and Wq|Wk|Wv (3x1M fp32) to one bf16 buffer.
// ---------------------------------------------------------------------------
__global__ __launch_bounds__(256)
void cast_all(const float* __restrict__ x,
              const float* __restrict__ Wq, const float* __restrict__ Wk,
              const float* __restrict__ Wv, bf16_t* __restrict__ dst)
{
    const size_t idx = ((size_t)blockIdx.x * 256 + threadIdx.x) * 4;
    const float* src;
    size_t off;
    if (idx < (size_t)M_TOT * H_DIM) { src = x; off = idx; }
    else {
        size_t j = idx - (size_t)M_TOT * H_DIM;
        int z = (int)(j >> 20);
        off = j & ((1u << 20) - 1);
        src = (z == 0) ? Wq : (z == 1) ? Wk : Wv;
    }
    const float4 v = *(const float4*)(src + off);
    bf16x4 o;
    o[0] = (bf16_t)v.x; o[1] = (bf16_t)v.y;
    o[2] = (bf16_t)v.z; o[3] = (bf16_t)v.w;
    *(bf16x4*)(dst + idx) = o;
}

// ---------------------------------------------------------------------------
// Kernel 1: QKV GEMM v2 — measured-best version (UNCHANGED from r6).
// One block = one (bm,bn) x ALL THREE weights; triple-buffered LDS + 2-deep
// DMA prefetch + vmcnt(8) own-slice wait THEN barrier.
// z=0 -> Q [bh][l][d], z=1 -> K [bh][l][d], z=2 -> V^T [bh][d][l].
// ---------------------------------------------------------------------------
__global__ __launch_bounds__(256, 1)
void qkv_mfma(const bf16_t* __restrict__ xb, const bf16_t* __restrict__ wb,
              const float* __restrict__ bq, const float* __restrict__ bk,
              const float* __restrict__ bv,
              bf16_t* __restrict__ qb, bf16_t* __restrict__ kb,
              bf16_t* __restrict__ vt)
{
    __shared__ bf16_t As0[128 * 32];
    __shared__ bf16_t As1[128 * 32];
    __shared__ bf16_t As2[128 * 32];
    __shared__ bf16_t Bs0[3][128 * 32];
    __shared__ bf16_t Bs1[3][128 * 32];
    __shared__ bf16_t Bs2[3][128 * 32];

    const int tid = threadIdx.x;
    const int n   = blockIdx.x;          // 0..255
    const int bn  = (n & 7) * 128;       // XCD-local W slice (round-robin)
    const int bm  = (n >> 3) * 128;

    const int wave = tid >> 6;
    const int lane = tid & 63;
    const int lc   = lane & 15;
    const int quad = lane >> 4;
    const int wm   = wave >> 1;
    const int wn   = wave & 1;

    f32x4 acc[3][4][4];
    #pragma unroll
    for (int z = 0; z < 3; ++z)
        #pragma unroll
        for (int i = 0; i < 4; ++i)
            #pragma unroll
            for (int j = 0; j < 4; ++j)
                acc[z][i][j] = (f32x4){0.f, 0.f, 0.f, 0.f};

    const int srow = tid >> 2;
    const int sseg = tid & 3;
    const bf16_t* gA = xb + (size_t)(bm + srow) * H_DIM + (sseg ^ (srow & 3)) * 8;
    const bf16_t* gB = wb + (size_t)(bn + srow) * H_DIM + (sseg ^ (srow & 3)) * 8;
    const int woff = wave * 1024;   // bytes per wave slice of a 4 KB half-tile

    auto stage = [&](int k0, bf16_t* A_, bf16_t (*B_)[128 * 32]) {
        __builtin_amdgcn_global_load_lds((AS1)(gA + k0),
            (AS3)((char*)A_ + woff), 16, 0, 0);
        __builtin_amdgcn_global_load_lds((AS1)(gA + k0 + (size_t)64 * H_DIM),
            (AS3)((char*)A_ + woff + 4096), 16, 0, 0);
        #pragma unroll
        for (int z = 0; z < 3; ++z) {
            const bf16_t* g = gB + (size_t)z * H_DIM * H_DIM + k0;
            __builtin_amdgcn_global_load_lds((AS1)(g),
                (AS3)((char*)B_[z] + woff), 16, 0, 0);
            __builtin_amdgcn_global_load_lds((AS1)(g + (size_t)64 * H_DIM),
                (AS3)((char*)B_[z] + woff + 4096), 16, 0, 0);
        }
    };

    const int slot = (quad ^ (lc & 3)) * 8;
    auto compute = [&](const bf16_t* A_, const bf16_t (*B_)[128 * 32]) {
        bf16x8 a[4];
        #pragma unroll
        for (int mi = 0; mi < 4; ++mi)
            a[mi] = *(const bf16x8*)(A_ + (wm * 64 + mi * 16 + lc) * 32 + slot);
        #pragma unroll
        for (int z = 0; z < 3; ++z) {
            bf16x8 b[4];
            #pragma unroll
            for (int ni = 0; ni < 4; ++ni)
                b[ni] = *(const bf16x8*)(B_[z] + (wn * 64 + ni * 16 + lc) * 32 + slot);
            #pragma unroll
            for (int mi = 0; mi < 4; ++mi)
                #pragma unroll
                for (int ni = 0; ni < 4; ++ni)
                    acc[z][mi][ni] = __builtin_amdgcn_mfma_f32_16x16x32_bf16(
                        a[mi], b[ni], acc[z][mi][ni], 0, 0, 0);
        }
    };

    auto step = [&](int kk, bf16_t* cA, bf16_t (*cB)[128 * 32],
                    bf16_t* nA, bf16_t (*nB)[128 * 32], bool doStage) {
        __builtin_amdgcn_s_waitcnt(0x0F78);   // vmcnt(8): 8 newest may remain
        __builtin_amdgcn_s_barrier();
        if (doStage) stage((kk + 2) * 32, nA, nB);
        compute(cA, cB);
    };

    stage(0,  As0, Bs0);
    stage(32, As1, Bs1);
    #pragma unroll 1
    for (int t = 0; t < 10; ++t) {
        const int kk = t * 3;
        step(kk,     As0, Bs0, As2, Bs2, true);
        step(kk + 1, As1, Bs1, As0, Bs0, true);
        step(kk + 2, As2, Bs2, As1, Bs1, true);
    }
    step(30, As0, Bs0, As2, Bs2, false);      // set 32 does not exist
    __builtin_amdgcn_s_waitcnt(0x0F70);       // vmcnt(0): set 31 landed
    __builtin_amdgcn_s_barrier();
    compute(As1, Bs1);                        // set 31

    // --- epilogue: bias + scatter per z ---
    const int nb = bn + wn * 64;
    #pragma unroll
    for (int z = 0; z < 3; ++z) {
        const float* bias = (z == 0) ? bq : (z == 1) ? bk : bv;
        float biasv[4];
        #pragma unroll
        for (int ni = 0; ni < 4; ++ni) biasv[ni] = bias[nb + ni * 16 + lc];

        #pragma unroll
        for (int mi = 0; mi < 4; ++mi) {
            const int m0 = bm + wm * 64 + mi * 16 + quad * 4;
            if (z == 2) {
                const int b_ = m0 >> 11;
                const int l0 = m0 & 2047;
                #pragma unroll
                for (int ni = 0; ni < 4; ++ni) {
                    const int nn = nb + ni * 16 + lc;
                    const int h = nn >> 6, d = nn & 63;
                    bf16x4 pk;
                    #pragma unroll
                    for (int r = 0; r < 4; ++r)
                        pk[r] = (bf16_t)(acc[z][mi][ni][r] + biasv[ni]);
                    *(bf16x4*)(vt + (((size_t)(b_ * NH + h)) * HD + d) * L_DIM + l0) = pk;
                }
            } else {
                bf16_t* dst = (z == 0) ? qb : kb;
                #pragma unroll
                for (int r = 0; r < 4; ++r) {
                    const int m  = m0 + r;
                    const int b_ = m >> 11;
                    const int l  = m & 2047;
                    #pragma unroll
                    for (int ni = 0; ni < 4; ++ni) {
                        const int nn = nb + ni * 16 + lc;
                        const int h = nn >> 6, d = nn & 63;
                        dst[(((size_t)(b_ * NH + h)) * L_DIM + l) * HD + d] =
                            (bf16_t)(acc[z][mi][ni][r] + biasv[ni]);
                    }
                }
            }
        }
    }
}

// ---------------------------------------------------------------------------
// Kernel 2: MFMA flash attention — r6 version (UNCHANGED).  4 q-waves share
// the K/V LDS double buffer; S=2 key split; mask bias precomputed in LDS;
// s_setprio around MFMA clusters.  (r7's last-finisher combine fusion is
// REVERTED: device-scope fence per block = L2 writeback on non-coherent
// XCDs -> 3.6x regression.  Cross-block combine stays at a kernel boundary.)
// ---------------------------------------------------------------------------
#define EXP_C   0.180336879f   /* 0.125 * log2(e) */
#define LOG2E   1.442695041f
#define EXP_SH  11.541560327f  /* 8 * log2(e) */

__device__ __forceinline__ void attn_tile32(
    int kbase, bool pre,
    const bf16_t* curK, const bf16_t* curV,
    bf16_t* nxtK, bf16_t* nxtV,
    const bf16_t* gKw, const bf16_t* gVw, int wo,
    bf16_t* Ps, const float* mvsL, int lc, int quad,
    const bf16x8 (&bQ)[2][2], f32x4 (&o)[2][4], float (&rs)[2])
{
    // Own DMA slice of THIS tile (issued one tile ago) landed, then barrier:
    // all waves' slices landed AND all waves finished reading the buffer the
    // upcoming prefetch will overwrite.
    __builtin_amdgcn_s_waitcnt(0x0F70);   // vmcnt(0)
    __builtin_amdgcn_s_barrier();

    const int e = lc & 7;

    // --- K fragment reads (swizzled) ---
    bf16x8 kf[2][2];
    #pragma unroll
    for (int ni = 0; ni < 2; ++ni) {
        const bf16_t* p = curK + (ni * 16 + lc) * 64;
        kf[ni][0] = *(const bf16x8*)(p + ((quad ^ e) << 3));
        kf[ni][1] = *(const bf16x8*)(p + (((quad ^ e) ^ 4) << 3));
    }

    // --- fire-and-forget DMA of the next tile (this wave's 1+1 slices) ---
    if (pre) {
        const int nk = kbase + 32;
        __builtin_amdgcn_global_load_lds(
            (AS1)(gKw + (size_t)nk * 64),
            (AS3)(nxtK + wo), 16, 0, 0);
        __builtin_amdgcn_global_load_lds(
            (AS1)(gVw + nk),
            (AS3)(nxtV + wo), 16, 0, 0);
    }

    // --- mask bias: precomputed in LDS (broadcast reads, no VALU) ---
    f32x4 mvs[2];
    #pragma unroll
    for (int ni = 0; ni < 2; ++ni)
        mvs[ni] = *(const f32x4*)(mvsL + kbase + ni * 16 + quad * 4);

    // --- S^T = K Q^T, exp2, P write (128B-row combined layout) ---
    #pragma unroll
    for (int f = 0; f < 2; ++f) {
        f32x4 s[2];
        __builtin_amdgcn_s_setprio(1);
        #pragma unroll
        for (int ni = 0; ni < 2; ++ni) {
            f32x4 t = (f32x4){0.f, 0.f, 0.f, 0.f};
            t = __builtin_amdgcn_mfma_f32_16x16x32_bf16(kf[ni][0], bQ[f][0], t, 0, 0, 0);
            t = __builtin_amdgcn_mfma_f32_16x16x32_bf16(kf[ni][1], bQ[f][1], t, 0, 0, 0);
            s[ni] = t;
        }
        __builtin_amdgcn_s_setprio(0);
        float acc = 0.f;
        #pragma unroll
        for (int ni = 0; ni < 2; ++ni) {
            bf16x4 pk;
            #pragma unroll
            for (int r = 0; r < 4; ++r) {
                const float p = __builtin_amdgcn_exp2f(s[ni][r] * EXP_C + mvs[ni][r]);
                acc += p;
                pk[r] = (bf16_t)p;
            }
            const int c = f * 4 + ni * 2 + (quad >> 1);     // logical chunk
            *(bf16x4*)(Ps + lc * 64 + ((c ^ e) << 3) + ((quad & 1) << 2)) = pk;
        }
        rs[f] += acc;
    }

    // --- V fragment reads (pair-interleaved swizzle) ---
    bf16x8 vf[4];
    const int e2 = lc >> 1;
    #pragma unroll
    for (int dg = 0; dg < 4; ++dg) {
        const int p  = dg * 8 + (lc >> 1);
        const int ch = (((lc & 1) << 2) + quad) ^ e2;
        vf[dg] = *(const bf16x8*)(curV + p * 64 + (ch << 3));
    }

    // --- O^T += V^T P^T ---
    #pragma unroll
    for (int f = 0; f < 2; ++f) {
        const int c = f * 4 + quad;
        const bf16x8 bP = *(const bf16x8*)(Ps + lc * 64 + ((c ^ e) << 3));
        __builtin_amdgcn_s_setprio(1);
        #pragma unroll
        for (int dg = 0; dg < 4; ++dg)
            o[f][dg] = __builtin_amdgcn_mfma_f32_16x16x32_bf16(vf[dg], bP, o[f][dg], 0, 0, 0);
        __builtin_amdgcn_s_setprio(0);
    }
}

__global__ __launch_bounds__(256, 4)
void attn_mfma(const bf16_t* __restrict__ qb, const bf16_t* __restrict__ kb,
               const bf16_t* __restrict__ vt, const float* __restrict__ mask,
               float* __restrict__ out, float* __restrict__ o1,
               float* __restrict__ l0, float* __restrict__ l1)
{
    __shared__ bf16_t Ks0[32 * 64];
    __shared__ bf16_t Ks1[32 * 64];
    __shared__ bf16_t Vs0[32 * 64];
    __shared__ bf16_t Vs1[32 * 64];
    __shared__ bf16_t Ps[4][16 * 64];   // per-wave P scratch
    __shared__ float  Ms[1024];         // precomputed mask*LOG2E - EXP_SH

    const int tid  = threadIdx.x;
    const int wave = tid >> 6;         // 0..3
    const int lane = tid & 63;
    const int lc   = lane & 15;
    const int quad = lane >> 4;
    const int rl   = lane >> 3;        // DMA row-in-group
    const int sg   = lane & 7;         // DMA 16B-seg (pre-swizzle)

    // XCD-locality decode: all blocks of a head on one XCD.
    const int n    = blockIdx.x;       // 0..1023
    const int bh   = (n & 7) * 4 + ((n >> 3) & 3);
    const int q0   = ((n >> 5) & 15) * 128 + wave * 32;
    const int ks   = (n >> 9) & 1;     // key half
    const int k0   = ks << 10;         // 0 or 1024
    const int b_   = bh >> 4;
    const int h    = bh & 15;

    bf16_t* Psw = Ps[wave];

    // Q fragments (B-operand of S^T): frag f holds q = q0 + f*16 + lc
    bf16x8 bQ[2][2];
    #pragma unroll
    for (int f = 0; f < 2; ++f) {
        const bf16_t* Qp = qb + ((size_t)bh * L_DIM + q0 + f * 16 + lc) * HD + quad * 8;
        bQ[f][0] = *(const bf16x8*)(Qp);
        bQ[f][1] = *(const bf16x8*)(Qp + 32);
    }

    const bf16_t* Kbase = kb + (size_t)bh * L_DIM * HD;   // [key][d]
    const bf16_t* Vbase = vt + (size_t)bh * HD * L_DIM;   // [d][key]
    const float*  mrow  = mask + (size_t)b_ * L_DIM + k0;

    // Precompute mask bias for this block's 1024 keys (shared by all waves).
    {
        const float4 m4 = *(const float4*)(mrow + tid * 4);
        f32x4 w;
        w[0] = m4.x * LOG2E - EXP_SH;
        w[1] = m4.y * LOG2E - EXP_SH;
        w[2] = m4.z * LOG2E - EXP_SH;
        w[3] = m4.w * LOG2E - EXP_SH;
        *(f32x4*)(Ms + tid * 4) = w;
    }

    // Per-lane DMA source bases; each wave owns 1 of the 4 K slices
    // (8 keys) and 1 of the 4 V slices (16 d-rows).
    const int cV = sg ^ rl;
    const bf16_t* gKw = Kbase + (size_t)(k0 + wave * 8 + rl) * 64 + (sg ^ rl) * 8;
    const bf16_t* gVw = Vbase + k0
                      + (size_t)(wave * 16 + rl * 2 + (cV >> 2)) * L_DIM
                      + (cV & 3) * 8;
    const int wo = wave * 512;         // element offset of this wave's slice

    f32x4 o[2][4];
    #pragma unroll
    for (int f = 0; f < 2; ++f)
        #pragma unroll
        for (int dg = 0; dg < 4; ++dg) o[f][dg] = (f32x4){0.f, 0.f, 0.f, 0.f};
    float rs[2] = {0.f, 0.f};

    // Prologue: DMA tile 0 (this wave's slices) into buffer 0.
    __builtin_amdgcn_global_load_lds((AS1)(gKw), (AS3)(Ks0 + wo), 16, 0, 0);
    __builtin_amdgcn_global_load_lds((AS1)(gVw), (AS3)(Vs0 + wo), 16, 0, 0);

    __syncthreads();   // Ms visible to all waves (full lgkm drain + barrier)

    #pragma unroll 1
    for (int t2 = 0; t2 < 16; ++t2) {
        const int kb0 = t2 * 64;
        attn_tile32(kb0,      true,     Ks0, Vs0, Ks1, Vs1, gKw, gVw, wo, Psw,
                    Ms, lc, quad, bQ, o, rs);
        attn_tile32(kb0 + 32, t2 < 15,  Ks1, Vs1, Ks0, Vs0, gKw, gVw, wo, Psw,
                    Ms, lc, quad, bQ, o, rs);
    }

    // --- epilogue: reduce l across quads, write UNNORMALIZED partial ---
    float* obase = (ks == 0) ? out : o1;
    float* lbase = (ks == 0) ? l0  : l1;
    #pragma unroll
    for (int f = 0; f < 2; ++f) {
        float l = rs[f];
        l += __shfl_xor(l, 16);
        l += __shfl_xor(l, 32);
        if (quad == 0)
            lbase[(size_t)bh * L_DIM + q0 + f * 16 + lc] = l;
        float* orow = obase + ((size_t)(b_ * L_DIM + q0 + f * 16 + lc)) * H_DIM
                    + h * HD + quad * 4;
        #pragma unroll
        for (int dg = 0; dg < 4; ++dg)
            *(f32x4*)(orow + dg * 16) = o[f][dg];
    }
}

// ---------------------------------------------------------------------------
// Kernel 3: combine the two key-half partials (separate dispatch — kernel
// boundary = single cheap coherence flush).  out = (O0+O1)/(l0+l1).
// 8 floats/thread (2x f32x4) for more memory-level parallelism per thread.
// ---------------------------------------------------------------------------
__global__ __launch_bounds__(256)
void attn_combine(const float* __restrict__ o1,
                  const float* __restrict__ l0, const float* __restrict__ l1,
                  float* __restrict__ out)
{
    const size_t idx = ((size_t)blockIdx.x * 256 + threadIdx.x) * 8;
    const int m   = (int)(idx >> 10);      // q-row (b*2048 + q)
    const int col = (int)(idx & 1023);     // h*64 + d (8-aligned, same h for +4)
    const int b_  = m >> 11;
    const int q   = m & 2047;
    const int h   = col >> 6;
    const size_t lidx = ((size_t)(b_ * NH + h)) * L_DIM + q;
    const float inv = 1.0f / (l0[lidx] + l1[lidx]);
    f32x4 a0 = *(const f32x4*)(out + idx);
    f32x4 a1 = *(const f32x4*)(out + idx + 4);
    const f32x4 b0 = *(const f32x4*)(o1 + idx);
    const f32x4 b1 = *(const f32x4*)(o1 + idx + 4);
    a0 = (a0 + b0) * inv;
    a1 = (a1 + b1) * inv;
    *(f32x4*)(out + idx)     = a0;
    *(f32x4*)(out + idx + 4) = a1;
}

// ---------------------------------------------------------------------------
extern "C" void kernel_launch(void* const* d_in, const int* in_sizes, int n_in,
                              void* d_out, int out_size, void* d_ws, size_t ws_size,
                              hipStream_t stream) {
    const float* hidden = (const float*)d_in[0];
    const float* mask   = (const float*)d_in[1];
    const float* Wq     = (const float*)d_in[2];
    const float* bq     = (const float*)d_in[3];
    const float* Wk     = (const float*)d_in[4];
    const float* bk     = (const float*)d_in[5];
    const float* Wv     = (const float*)d_in[6];
    const float* bv     = (const float*)d_in[7];
    float* out = (float*)d_out;

    const size_t XN = (size_t)M_TOT * H_DIM;     // 4,194,304
    const size_t WN = (size_t)3 * H_DIM * H_DIM; // 3,145,728
    bf16_t* xwb = (bf16_t*)d_ws;
    bf16_t* qb  = xwb + XN + WN;
    bf16_t* kb  = qb + XN;
    bf16_t* vt  = kb + XN;
    float*  o1  = (float*)(vt + XN);             // key-half-1 partial O (fp32)
    float*  l0  = o1 + XN;                       // 65536 f32 each
    float*  l1  = l0 + (size_t)B_DIM * NH * L_DIM;

    cast_all<<<(int)((XN + WN) / 1024), 256, 0, stream>>>(hidden, Wq, Wk, Wv, xwb);

    qkv_mfma<<<256, 256, 0, stream>>>(xwb, xwb + XN, bq, bk, bv, qb, kb, vt);

    attn_mfma<<<1024, 256, 0, stream>>>(qb, kb, vt, mask, out, o1, l0, l1);

    attn_combine<<<2048, 256, 0, stream>>>(o1, l0, l1, out);
}